// Round 14
// baseline (85.275 us; speedup 1.0000x reference)
//
#include <hip/hip_runtime.h>
#include <cstdint>

typedef unsigned long long u64;
typedef unsigned int u32;

// Problem constants (mirroring the reference)
constexpr int VBITS = 12;
constexpr int VOFF  = 1 << (VBITS - 1);   // 2048
constexpr int GBITS = 10;                 // G = 1024

constexpr int GPB = 16;   // groups per block
constexpr int WPB = 4;    // waves per block (256 threads)
constexpr int GPW = 4;    // groups per wave

// 64-lane bitonic sort (ascending), one u32 per lane.
__device__ inline u32 wave_sort_u32(u32 k, int lane) {
    #pragma unroll
    for (int ks = 2; ks <= 64; ks <<= 1) {
        #pragma unroll
        for (int j = ks >> 1; j >= 1; j >>= 1) {
            u32 other = __shfl_xor(k, j, 64);
            bool takeMin = ((lane & ks) == 0) == ((lane & j) == 0);
            u32 mn = min(k, other), mx = max(k, other);
            k = takeMin ? mn : mx;
        }
    }
    return k;
}

// 64-lane bitonic sort (ascending), one u64 per lane (rare fallback path).
__device__ inline u64 wave_sort_u64(u64 k, int lane) {
    #pragma unroll
    for (int ks = 2; ks <= 64; ks <<= 1) {
        #pragma unroll
        for (int j = ks >> 1; j >= 1; j >>= 1) {
            u64 other = __shfl_xor(k, j, 64);
            bool takeMin = ((lane & ks) == 0) == ((lane & j) == 0);
            u64 mn = k < other ? k : other;
            u64 mx = k < other ? other : k;
            k = takeMin ? mn : mx;
        }
    }
    return k;
}

// convergent cross-lane push: lane (idx) receives src of this lane
__device__ inline u32 lane_push(int dest_lane, u32 src) {
    return (u32)__builtin_amdgcn_ds_permute(dest_lane << 2, (int)src);
}

// ---------------------------------------------------------------------------
// Kernel 1: build (byte-identical logic to R13 — proven exact, idempotent).
// ---------------------------------------------------------------------------
__global__ __launch_bounds__(256) void vox_build(
    const float* __restrict__ pred,
    u32* __restrict__ arr,         // [ngroups*64]
    u64* __restrict__ meta,        // [ngroups]
    u32* __restrict__ blockSums,   // [nblocks]
    int ngroups)
{
    __shared__ float sf[GPB * 192];   // 12 KB staged pred
    __shared__ u32 s_ws[WPB];
    const int t = threadIdx.x, w = t >> 6, lane = t & 63, b = blockIdx.x;

    // float4-vectorized staging
    {
        const float4* p4 = (const float4*)pred + (size_t)b * (GPB * 48);
        const size_t f4tot = (size_t)ngroups * 48;
        float4* s4 = (float4*)sf;
        #pragma unroll
        for (int i = 0; i < 3; i++) {
            int idx = t + i * 256;
            if ((size_t)b * (GPB * 48) + idx < f4tot) s4[idx] = p4[idx];
        }
    }
    __syncthreads();

    u32 wsum = 0;
    for (int j = 0; j < GPW; ++j) {
        int gi = w * GPW + j, gid = b * GPB + gi;
        if (gid < ngroups) {   // wave-uniform
            const float* q = sf + gi * 192 + lane * 3;
            // exactly as reference: floor(x / 0.1f) in f32 (IEEE divide)
            int v0 = (int)floorf(q[0] / 0.1f) + VOFF;
            int v1 = (int)floorf(q[1] / 0.1f) + VOFF;
            int v2 = (int)floorf(q[2] / 0.1f) + VOFF;
            int r0 = __shfl(v0, 0, 64), r1 = __shfl(v1, 0, 64), r2 = __shfl(v2, 0, 64);
            int d0 = v0 - r0 + 128, d1 = v1 - r1 + 128, d2 = v2 - r2 + 128;
            bool bad = ((u32)(d0 | d1 | d2) > 255u) || ((u32)(v0 | v1 | v2) > 4095u);

            u32 cnt, packed;
            if (!__any(bad)) {
                u32 k = ((u32)d0 << 22) | ((u32)d1 << 14) | ((u32)d2 << 6) | (u32)lane;
                k = wave_sort_u32(k, lane);
                u32 sk = k >> 6;                       // delta24
                u32 pv = __shfl_up(sk, 1, 64);
                int flag = (lane == 0 || sk != pv) ? 1 : 0;
                u64 bal = __ballot(flag);
                int rank = (int)__popcll(bal & ((1ull << lane) - 1ull)) + flag - 1;
                cnt = (u32)__popcll(bal);
                int orig = (int)(k & 63);

                u32 dByRank = lane_push(rank, sk);        // delta of rank==lane
                u32 rByOrig = lane_push(orig, (u32)rank); // rank of point lane
                packed = (dByRank & 0xFFFFFFu) | (rByOrig << 24);

                if (lane == 0)
                    meta[gid] = ((u64)((u32)(r0 - 128) & 4095))
                              | ((u64)((u32)(r1 - 128) & 4095) << 12)
                              | ((u64)((u32)(r2 - 128) & 4095) << 24)
                              | ((u64)cnt << 48);
            } else {
                u64 code = ((u64)(long long)v0 << 24) | ((u64)(long long)v1 << 12)
                         | (u64)(long long)v2;
                u64 k = wave_sort_u64((code << 6) | (u64)lane, lane);
                u64 sk = k >> 6, pv = __shfl_up(sk, 1, 64);
                int flag = (lane == 0 || sk != pv) ? 1 : 0;
                u64 bal = __ballot(flag);
                int rank = (int)__popcll(bal & ((1ull << lane) - 1ull)) + flag - 1;
                cnt = (u32)__popcll(bal);
                int orig = (int)(k & 63);
                u32 rByOrig = lane_push(orig, (u32)rank);
                packed = rByOrig << 24;    // rank only; emit re-derives codes
                if (lane == 0) meta[gid] = ((u64)cnt << 48) | (1ull << 56);
            }
            arr[(size_t)gid * 64 + lane] = packed;
            wsum += cnt;
        }
    }
    if (lane == 0) s_ws[w] = wsum;
    __syncthreads();
    if (t == 0) blockSums[b] = s_ws[0] + s_ws[1] + s_ws[2] + s_ws[3];
}

// ---------------------------------------------------------------------------
// Kernel 2: emit (byte-identical logic to R13).
// ---------------------------------------------------------------------------
__global__ __launch_bounds__(256) void vox_emit(
    const float* __restrict__ pred,
    const u32* __restrict__ arr,
    const u64* __restrict__ meta,
    const u32* __restrict__ blockSums,
    int* __restrict__ okeys,     // [totalrows * 5] int32
    int* __restrict__ inv,       // [totalrows]     int32
    int ngroups, int totalrows, int nblocks)
{
    __shared__ u32 s_scr[512];          // scan scratch
    __shared__ u32 s_c[GPB];
    __shared__ u32 s_baseU[2];
    __shared__ int s_tail[5];
    const int t = threadIdx.x, w = t >> 6, lane = t & 63, b = blockIdx.x;

    // batched per-wave loads for all 4 groups (independent, issued early)
    u32 a[GPW]; u64 m[GPW];
    #pragma unroll
    for (int j = 0; j < GPW; ++j) {
        int gid = b * GPB + w * GPW + j;
        if (gid < ngroups) {
            a[j] = arr[(size_t)gid * 64 + lane];
            m[j] = meta[gid];
        } else { a[j] = 0; m[j] = 0; }
    }

    if (t < GPB) {
        int gid = b * GPB + t;
        s_c[t] = (gid < ngroups) ? (u32)((meta[gid] >> 48) & 127) : 0;
    }

    // redundant scan: below = sum(blockSums[i<b]), all = total U
    {
        u32 below = 0, all = 0;
        for (int i = t; i < nblocks; i += 256) {
            u32 v = blockSums[i];
            all += v;
            if (i < b) below += v;
        }
        __syncthreads();   // s_c ready too
        s_scr[t] = below; s_scr[256 + t] = all;
        __syncthreads();
        #pragma unroll
        for (int off = 128; off >= 1; off >>= 1) {
            if (t < off) {
                s_scr[t]       += s_scr[t + off];
                s_scr[256 + t] += s_scr[256 + t + off];
            }
            __syncthreads();
        }
        if (t == 0) { s_baseU[0] = s_scr[0]; s_baseU[1] = s_scr[256]; }
        __syncthreads();
    }

    u32 base = s_baseU[0];
    #pragma unroll
    for (int i = 0; i < GPB; i++) if (i < w * GPW) base += s_c[i];

    #pragma unroll
    for (int j = 0; j < GPW; ++j) {
        int gid = b * GPB + w * GPW + j;
        if (gid < ngroups) {   // wave-uniform
            u32 cnt = (u32)((m[j] >> 48) & 127);
            u32 rinv = a[j] >> 24;

            // coalesced inverse-index write
            inv[(size_t)gid * 64 + lane] = (int)(base + rinv);

            int vd0 = 0, vd1 = 0, vd2 = 0;
            if (!((m[j] >> 56) & 1)) {
                // fast path: decode rank==lane row straight from arr
                u32 d = a[j] & 0xFFFFFFu;
                u32 m0 = (u32)m[j] & 4095, m1 = (u32)(m[j] >> 12) & 4095,
                    m2 = (u32)(m[j] >> 24) & 4095;
                vd0 = (int)((m0 + ((d >> 16) & 255)) & 4095);
                vd1 = (int)((m1 + ((d >> 8) & 255)) & 4095);
                vd2 = (int)((m2 + (d & 255)) & 4095);
            } else {
                // rare exact path: recompute own code, push it to lane==rank
                const float* p = pred + (size_t)gid * 192 + lane * 3;
                long long w0 = (long long)floorf(p[0] / 0.1f) + VOFF;
                long long w1 = (long long)floorf(p[1] / 0.1f) + VOFF;
                long long w2 = (long long)floorf(p[2] / 0.1f) + VOFF;
                u64 code = ((u64)w0 << 24) | ((u64)w1 << 12) | (u64)w2;
                u32 clo = (u32)__builtin_amdgcn_ds_permute((int)(rinv << 2), (int)(u32)code);
                u32 chi = (u32)__builtin_amdgcn_ds_permute((int)(rinv << 2), (int)(u32)(code >> 32));
                u64 c = ((u64)chi << 32) | clo;
                vd0 = (int)((c >> 24) & 4095);
                vd1 = (int)((c >> 12) & 4095);
                vd2 = (int)(c & 4095);
            }

            // direct row store: ranks are dense, region stays contiguous
            if (lane < (int)cnt) {
                int* dst = okeys + (size_t)(base + lane) * 5;
                dst[0] = gid >> GBITS;               // b
                dst[1] = gid & ((1 << GBITS) - 1);   // g
                dst[2] = vd0 - VOFF;
                dst[3] = vd1 - VOFF;
                dst[4] = vd2 - VOFF;
            }
            base += cnt;
        }
    }

    // tail fill: rows [U, totalrows) replicate the global max row
    if (w == 0) {
        int lg = ngroups - 1;
        const float* p = pred + (size_t)lg * 192 + lane * 3;
        long long w0 = (long long)floorf(p[0] / 0.1f) + VOFF;
        long long w1 = (long long)floorf(p[1] / 0.1f) + VOFF;
        long long w2 = (long long)floorf(p[2] / 0.1f) + VOFF;
        u64 code = ((u64)w0 << 24) | ((u64)w1 << 12) | (u64)w2;
        #pragma unroll
        for (int off = 32; off >= 1; off >>= 1) {
            u64 o = __shfl_xor(code, off, 64);
            code = (o > code) ? o : code;
        }
        if (lane == 0) {
            s_tail[0] = lg >> GBITS;
            s_tail[1] = lg & ((1 << GBITS) - 1);
            s_tail[2] = (int)((code >> 24) & 4095) - VOFF;
            s_tail[3] = (int)((code >> 12) & 4095) - VOFF;
            s_tail[4] = (int)(code & 4095) - VOFF;
        }
    }
    __syncthreads();
    {
        u32 U = s_baseU[1];
        u32 total5 = (u32)totalrows * 5u;
        u32 stride = (u32)gridDim.x * 256u;
        for (u32 e = U * 5u + (u32)b * 256u + (u32)t; e < total5; e += stride)
            okeys[e] = s_tail[e % 5u];
    }
}

extern "C" void kernel_launch(void* const* d_in, const int* in_sizes, int n_in,
                              void* d_out, int out_size, void* d_ws, size_t ws_size,
                              hipStream_t stream)
{
    const float* pred = (const float*)d_in[0];
    // active_mask is all-true by construction -> group n = (b<<10)|g = n
    int ngroups   = in_sizes[1];                  // 65536
    int totalrows = in_sizes[0] / 3;              // N*P = 4194304
    int nblocks   = (ngroups + GPB - 1) / GPB;    // 4096

    int* okeys = (int*)d_out;                     // [totalrows][5] int32
    int* inv   = okeys + (size_t)totalrows * 5;   // [totalrows]    int32

    char* ws = (char*)d_ws;
    u64* meta      = (u64*)ws;                                  // 512 KB
    u32* arr       = (u32*)(meta + ngroups);                    // 16 MB
    u32* blockSums = arr + (size_t)ngroups * 64;                // 16 KB

    // MEASUREMENT ROUND: build launched twice (idempotent — writes identical
    // data both times). dur_R14 - dur_R13 isolates build+gap cost.
    vox_build<<<nblocks, 256, 0, stream>>>(pred, arr, meta, blockSums, ngroups);
    vox_build<<<nblocks, 256, 0, stream>>>(pred, arr, meta, blockSums, ngroups);
    vox_emit<<<nblocks, 256, 0, stream>>>(pred, arr, meta, blockSums,
                                          okeys, inv, ngroups, totalrows, nblocks);
}

// Round 15
// 54.418 us; speedup vs baseline: 1.5670x; 1.5670x over previous
//
#include <hip/hip_runtime.h>
#include <cstdint>

typedef unsigned long long u64;
typedef unsigned int u32;

// Problem constants (mirroring the reference)
constexpr int VBITS = 12;
constexpr int VOFF  = 1 << (VBITS - 1);   // 2048
constexpr int GBITS = 10;                 // G = 1024

constexpr int GPB = 16;   // groups per block
constexpr int WPB = 4;    // waves per block (256 threads)
constexpr int GPW = 4;    // groups per wave

// Butterfly partner exchange, pipe-optimized:
//  j=1,2  -> DPP quad_perm (VALU pipe, no DS)
//  j=4,8,16 -> ds_swizzle XOR bit-mode (DS, but no addr-calc VALU)
//  j=32   -> shfl_xor (ds_bpermute)
__device__ inline u32 partner_xor(u32 k, int j) {
    switch (j) {
    case 1:  return (u32)__builtin_amdgcn_mov_dpp((int)k, 0xB1, 0xF, 0xF, true); // quad_perm [1,0,3,2]
    case 2:  return (u32)__builtin_amdgcn_mov_dpp((int)k, 0x4E, 0xF, 0xF, true); // quad_perm [2,3,0,1]
    case 4:  return (u32)__builtin_amdgcn_ds_swizzle((int)k, 0x101F);            // xor 4
    case 8:  return (u32)__builtin_amdgcn_ds_swizzle((int)k, 0x201F);            // xor 8
    case 16: return (u32)__builtin_amdgcn_ds_swizzle((int)k, 0x401F);            // xor 16
    default: return (u32)__shfl_xor((int)k, 32, 64);                             // xor 32
    }
}

// 64-lane bitonic sort (ascending), one u32 per lane.
__device__ inline u32 wave_sort_u32(u32 k, int lane) {
    #pragma unroll
    for (int ks = 2; ks <= 64; ks <<= 1) {
        #pragma unroll
        for (int j = ks >> 1; j >= 1; j >>= 1) {
            u32 other = partner_xor(k, j);
            bool takeMin = ((lane & ks) == 0) == ((lane & j) == 0);
            u32 mn = min(k, other), mx = max(k, other);
            k = takeMin ? mn : mx;
        }
    }
    return k;
}

// 64-lane bitonic sort (ascending), one u64 per lane (rare fallback path).
__device__ inline u64 wave_sort_u64(u64 k, int lane) {
    #pragma unroll
    for (int ks = 2; ks <= 64; ks <<= 1) {
        #pragma unroll
        for (int j = ks >> 1; j >= 1; j >>= 1) {
            u64 other = __shfl_xor(k, j, 64);
            bool takeMin = ((lane & ks) == 0) == ((lane & j) == 0);
            u64 mn = k < other ? k : other;
            u64 mx = k < other ? other : k;
            k = takeMin ? mn : mx;
        }
    }
    return k;
}

// convergent cross-lane push: lane (idx) receives src of this lane
__device__ inline u32 lane_push(int dest_lane, u32 src) {
    return (u32)__builtin_amdgcn_ds_permute(dest_lane << 2, (int)src);
}

// ---------------------------------------------------------------------------
// Kernel 1: build (logic identical to R13 — proven exact; sort pipe-optimized).
//   arr[gid*64 + lane] = (rank_of_original_point[lane] << 24)
//                      | (delta24 of the rank==lane distinct value)
//   meta[gid] = refs(36b) | cnt<<48 | fallback<<56.
// ---------------------------------------------------------------------------
__global__ __launch_bounds__(256) void vox_build(
    const float* __restrict__ pred,
    u32* __restrict__ arr,         // [ngroups*64]
    u64* __restrict__ meta,        // [ngroups]
    u32* __restrict__ blockSums,   // [nblocks]
    int ngroups)
{
    __shared__ float sf[GPB * 192];   // 12 KB staged pred
    __shared__ u32 s_ws[WPB];
    const int t = threadIdx.x, w = t >> 6, lane = t & 63, b = blockIdx.x;

    // float4-vectorized staging
    {
        const float4* p4 = (const float4*)pred + (size_t)b * (GPB * 48);
        const size_t f4tot = (size_t)ngroups * 48;
        float4* s4 = (float4*)sf;
        #pragma unroll
        for (int i = 0; i < 3; i++) {
            int idx = t + i * 256;
            if ((size_t)b * (GPB * 48) + idx < f4tot) s4[idx] = p4[idx];
        }
    }
    __syncthreads();

    u32 wsum = 0;
    for (int j = 0; j < GPW; ++j) {
        int gi = w * GPW + j, gid = b * GPB + gi;
        if (gid < ngroups) {   // wave-uniform
            const float* q = sf + gi * 192 + lane * 3;
            // exactly as reference: floor(x / 0.1f) in f32 (IEEE divide)
            int v0 = (int)floorf(q[0] / 0.1f) + VOFF;
            int v1 = (int)floorf(q[1] / 0.1f) + VOFF;
            int v2 = (int)floorf(q[2] / 0.1f) + VOFF;
            int r0 = __shfl(v0, 0, 64), r1 = __shfl(v1, 0, 64), r2 = __shfl(v2, 0, 64);
            int d0 = v0 - r0 + 128, d1 = v1 - r1 + 128, d2 = v2 - r2 + 128;
            bool bad = ((u32)(d0 | d1 | d2) > 255u) || ((u32)(v0 | v1 | v2) > 4095u);

            u32 cnt, packed;
            if (!__any(bad)) {
                u32 k = ((u32)d0 << 22) | ((u32)d1 << 14) | ((u32)d2 << 6) | (u32)lane;
                k = wave_sort_u32(k, lane);
                u32 sk = k >> 6;                       // delta24
                u32 pv = __shfl_up(sk, 1, 64);
                int flag = (lane == 0 || sk != pv) ? 1 : 0;
                u64 bal = __ballot(flag);
                int rank = (int)__popcll(bal & ((1ull << lane) - 1ull)) + flag - 1;
                cnt = (u32)__popcll(bal);
                int orig = (int)(k & 63);

                u32 dByRank = lane_push(rank, sk);        // delta of rank==lane
                u32 rByOrig = lane_push(orig, (u32)rank); // rank of point lane
                packed = (dByRank & 0xFFFFFFu) | (rByOrig << 24);

                if (lane == 0)
                    meta[gid] = ((u64)((u32)(r0 - 128) & 4095))
                              | ((u64)((u32)(r1 - 128) & 4095) << 12)
                              | ((u64)((u32)(r2 - 128) & 4095) << 24)
                              | ((u64)cnt << 48);
            } else {
                u64 code = ((u64)(long long)v0 << 24) | ((u64)(long long)v1 << 12)
                         | (u64)(long long)v2;
                u64 k = wave_sort_u64((code << 6) | (u64)lane, lane);
                u64 sk = k >> 6, pv = __shfl_up(sk, 1, 64);
                int flag = (lane == 0 || sk != pv) ? 1 : 0;
                u64 bal = __ballot(flag);
                int rank = (int)__popcll(bal & ((1ull << lane) - 1ull)) + flag - 1;
                cnt = (u32)__popcll(bal);
                int orig = (int)(k & 63);
                u32 rByOrig = lane_push(orig, (u32)rank);
                packed = rByOrig << 24;    // rank only; emit re-derives codes
                if (lane == 0) meta[gid] = ((u64)cnt << 48) | (1ull << 56);
            }
            arr[(size_t)gid * 64 + lane] = packed;
            wsum += cnt;
        }
    }
    if (lane == 0) s_ws[w] = wsum;
    __syncthreads();
    if (t == 0) blockSums[b] = s_ws[0] + s_ws[1] + s_ws[2] + s_ws[3];
}

// ---------------------------------------------------------------------------
// Kernel 2: emit (byte-identical logic to R13).
// ---------------------------------------------------------------------------
__global__ __launch_bounds__(256) void vox_emit(
    const float* __restrict__ pred,
    const u32* __restrict__ arr,
    const u64* __restrict__ meta,
    const u32* __restrict__ blockSums,
    int* __restrict__ okeys,     // [totalrows * 5] int32
    int* __restrict__ inv,       // [totalrows]     int32
    int ngroups, int totalrows, int nblocks)
{
    __shared__ u32 s_scr[512];          // scan scratch
    __shared__ u32 s_c[GPB];
    __shared__ u32 s_baseU[2];
    __shared__ int s_tail[5];
    const int t = threadIdx.x, w = t >> 6, lane = t & 63, b = blockIdx.x;

    // batched per-wave loads for all 4 groups (independent, issued early)
    u32 a[GPW]; u64 m[GPW];
    #pragma unroll
    for (int j = 0; j < GPW; ++j) {
        int gid = b * GPB + w * GPW + j;
        if (gid < ngroups) {
            a[j] = arr[(size_t)gid * 64 + lane];
            m[j] = meta[gid];
        } else { a[j] = 0; m[j] = 0; }
    }

    if (t < GPB) {
        int gid = b * GPB + t;
        s_c[t] = (gid < ngroups) ? (u32)((meta[gid] >> 48) & 127) : 0;
    }

    // redundant scan: below = sum(blockSums[i<b]), all = total U
    {
        u32 below = 0, all = 0;
        for (int i = t; i < nblocks; i += 256) {
            u32 v = blockSums[i];
            all += v;
            if (i < b) below += v;
        }
        __syncthreads();   // s_c ready too
        s_scr[t] = below; s_scr[256 + t] = all;
        __syncthreads();
        #pragma unroll
        for (int off = 128; off >= 1; off >>= 1) {
            if (t < off) {
                s_scr[t]       += s_scr[t + off];
                s_scr[256 + t] += s_scr[256 + t + off];
            }
            __syncthreads();
        }
        if (t == 0) { s_baseU[0] = s_scr[0]; s_baseU[1] = s_scr[256]; }
        __syncthreads();
    }

    u32 base = s_baseU[0];
    #pragma unroll
    for (int i = 0; i < GPB; i++) if (i < w * GPW) base += s_c[i];

    #pragma unroll
    for (int j = 0; j < GPW; ++j) {
        int gid = b * GPB + w * GPW + j;
        if (gid < ngroups) {   // wave-uniform
            u32 cnt = (u32)((m[j] >> 48) & 127);
            u32 rinv = a[j] >> 24;

            // coalesced inverse-index write
            inv[(size_t)gid * 64 + lane] = (int)(base + rinv);

            int vd0 = 0, vd1 = 0, vd2 = 0;
            if (!((m[j] >> 56) & 1)) {
                // fast path: decode rank==lane row straight from arr
                u32 d = a[j] & 0xFFFFFFu;
                u32 m0 = (u32)m[j] & 4095, m1 = (u32)(m[j] >> 12) & 4095,
                    m2 = (u32)(m[j] >> 24) & 4095;
                vd0 = (int)((m0 + ((d >> 16) & 255)) & 4095);
                vd1 = (int)((m1 + ((d >> 8) & 255)) & 4095);
                vd2 = (int)((m2 + (d & 255)) & 4095);
            } else {
                // rare exact path: recompute own code, push it to lane==rank
                const float* p = pred + (size_t)gid * 192 + lane * 3;
                long long w0 = (long long)floorf(p[0] / 0.1f) + VOFF;
                long long w1 = (long long)floorf(p[1] / 0.1f) + VOFF;
                long long w2 = (long long)floorf(p[2] / 0.1f) + VOFF;
                u64 code = ((u64)w0 << 24) | ((u64)w1 << 12) | (u64)w2;
                u32 clo = (u32)__builtin_amdgcn_ds_permute((int)(rinv << 2), (int)(u32)code);
                u32 chi = (u32)__builtin_amdgcn_ds_permute((int)(rinv << 2), (int)(u32)(code >> 32));
                u64 c = ((u64)chi << 32) | clo;
                vd0 = (int)((c >> 24) & 4095);
                vd1 = (int)((c >> 12) & 4095);
                vd2 = (int)(c & 4095);
            }

            // direct row store: ranks are dense, region stays contiguous
            if (lane < (int)cnt) {
                int* dst = okeys + (size_t)(base + lane) * 5;
                dst[0] = gid >> GBITS;               // b
                dst[1] = gid & ((1 << GBITS) - 1);   // g
                dst[2] = vd0 - VOFF;
                dst[3] = vd1 - VOFF;
                dst[4] = vd2 - VOFF;
            }
            base += cnt;
        }
    }

    // tail fill: rows [U, totalrows) replicate the global max row
    if (w == 0) {
        int lg = ngroups - 1;
        const float* p = pred + (size_t)lg * 192 + lane * 3;
        long long w0 = (long long)floorf(p[0] / 0.1f) + VOFF;
        long long w1 = (long long)floorf(p[1] / 0.1f) + VOFF;
        long long w2 = (long long)floorf(p[2] / 0.1f) + VOFF;
        u64 code = ((u64)w0 << 24) | ((u64)w1 << 12) | (u64)w2;
        #pragma unroll
        for (int off = 32; off >= 1; off >>= 1) {
            u64 o = __shfl_xor(code, off, 64);
            code = (o > code) ? o : code;
        }
        if (lane == 0) {
            s_tail[0] = lg >> GBITS;
            s_tail[1] = lg & ((1 << GBITS) - 1);
            s_tail[2] = (int)((code >> 24) & 4095) - VOFF;
            s_tail[3] = (int)((code >> 12) & 4095) - VOFF;
            s_tail[4] = (int)(code & 4095) - VOFF;
        }
    }
    __syncthreads();
    {
        u32 U = s_baseU[1];
        u32 total5 = (u32)totalrows * 5u;
        u32 stride = (u32)gridDim.x * 256u;
        for (u32 e = U * 5u + (u32)b * 256u + (u32)t; e < total5; e += stride)
            okeys[e] = s_tail[e % 5u];
    }
}

extern "C" void kernel_launch(void* const* d_in, const int* in_sizes, int n_in,
                              void* d_out, int out_size, void* d_ws, size_t ws_size,
                              hipStream_t stream)
{
    const float* pred = (const float*)d_in[0];
    // active_mask is all-true by construction -> group n = (b<<10)|g = n
    int ngroups   = in_sizes[1];                  // 65536
    int totalrows = in_sizes[0] / 3;              // N*P = 4194304
    int nblocks   = (ngroups + GPB - 1) / GPB;    // 4096

    int* okeys = (int*)d_out;                     // [totalrows][5] int32
    int* inv   = okeys + (size_t)totalrows * 5;   // [totalrows]    int32

    char* ws = (char*)d_ws;
    u64* meta      = (u64*)ws;                                  // 512 KB
    u32* arr       = (u32*)(meta + ngroups);                    // 16 MB
    u32* blockSums = arr + (size_t)ngroups * 64;                // 16 KB

    vox_build<<<nblocks, 256, 0, stream>>>(pred, arr, meta, blockSums, ngroups);
    vox_emit<<<nblocks, 256, 0, stream>>>(pred, arr, meta, blockSums,
                                          okeys, inv, ngroups, totalrows, nblocks);
}